// Round 1
// baseline (806.036 us; speedup 1.0000x reference)
//
#include <hip/hip_runtime.h>
#include <hip/hip_bf16.h>
#include <stdint.h>

// Problem constants (match reference)
#define NN 50000
#define NE 1600000
#define INC 116
#define K1P 128     // padded K for layer-1 GEMM
#define HID 256
#define OUTC 2

// ---------------- edge-index format hedge (int32 vs int64) ----------------
// If harness ships int64 (little-endian, values < 50000), every odd 32-bit
// word is 0. Detector checks 64 odd words; misdetect probability ~(1/5e4)^64.
__global__ void detect_fmt(const int* __restrict__ ebuf, int* __restrict__ flag) {
    int v = ebuf[2 * threadIdx.x + 1];
    unsigned long long b = __ballot(v != 0);
    if (threadIdx.x == 0) flag[0] = (b == 0ULL) ? 1 : 0;
}

__device__ __forceinline__ int edge_at(const int* __restrict__ ebuf, int is64, int idx) {
    return is64 ? ebuf[2 * idx] : ebuf[idx];
}

// ---------------- degree histogram ----------------
__global__ void deg_hist(const int* __restrict__ ebuf, const int* __restrict__ flag,
                         int* __restrict__ cnt) {
    int e = blockIdx.x * blockDim.x + threadIdx.x;
    if (e >= NE) return;
    int is64 = flag[0];
    int d = edge_at(ebuf, is64, NE + e);
    atomicAdd(&cnt[d], 1);
}

__global__ void dinv_kernel(const int* __restrict__ cnt, float* __restrict__ dinv) {
    int n = blockIdx.x * blockDim.x + threadIdx.x;
    if (n < NN) dinv[n] = rsqrtf((float)cnt[n] + 1.0f);
}

// ---------------- prefix scan (3 kernels, 256-wide blocks) ----------------
__global__ void scan1(const int* __restrict__ cnt, int* __restrict__ rowptr,
                      int* __restrict__ bsum) {
    __shared__ int s[256];
    int tid = threadIdx.x;
    int i = blockIdx.x * 256 + tid;
    int v = (i < NN) ? cnt[i] : 0;
    s[tid] = v;
    __syncthreads();
    for (int off = 1; off < 256; off <<= 1) {
        int t = (tid >= off) ? s[tid - off] : 0;
        __syncthreads();
        s[tid] += t;
        __syncthreads();
    }
    if (i < NN) rowptr[i] = s[tid] - v;            // exclusive
    if (tid == 255) bsum[blockIdx.x] = s[255];     // block total
}

__global__ void scan2(int* __restrict__ bsum, int nblocks) {
    __shared__ int s[256];
    int tid = threadIdx.x;
    int v = (tid < nblocks) ? bsum[tid] : 0;
    s[tid] = v;
    __syncthreads();
    for (int off = 1; off < 256; off <<= 1) {
        int t = (tid >= off) ? s[tid - off] : 0;
        __syncthreads();
        s[tid] += t;
        __syncthreads();
    }
    if (tid < nblocks) bsum[tid] = s[tid] - v;     // exclusive
}

__global__ void scan3(int* __restrict__ rowptr, const int* __restrict__ bsum,
                      int* __restrict__ fillpos) {
    int i = blockIdx.x * 256 + threadIdx.x;
    if (i < NN) {
        int r = rowptr[i] + bsum[blockIdx.x];
        rowptr[i] = r;
        fillpos[i] = r;
        if (i == NN - 1) rowptr[NN] = NE;
    }
}

__global__ void fill_csr(const int* __restrict__ ebuf, const int* __restrict__ flag,
                         int* __restrict__ fillpos, int* __restrict__ col) {
    int e = blockIdx.x * blockDim.x + threadIdx.x;
    if (e >= NE) return;
    int is64 = flag[0];
    int s = edge_at(ebuf, is64, e);
    int d = edge_at(ebuf, is64, NE + e);
    int p = atomicAdd(&fillpos[d], 1);
    col[p] = s;
}

// ---------------- zero-pad W1 116x256 -> 128x256 ----------------
__global__ void pad_w1(const float* __restrict__ W1, float* __restrict__ W1p) {
    int i = blockIdx.x * 256 + threadIdx.x;   // over 128*256
    int k = i >> 8;
    W1p[i] = (k < INC) ? W1[i - (k - 0) * 0 - (k * 256 - k * 256) + (k * 256 + (i & 255)) - i + 0 * 0] : 0.f;
}
// NOTE: simplified below (the above arithmetic is identity when k<INC since i = k*256 + c)

// ---------------- pull aggregation: out[n] = dinv[n]*(sum dinv[s]*h[s] + dinv[n]*h[n]) ----
// one block per node; channel = threadIdx.x; CIN = input row stride, COUT = output row stride
template <int CIN, int COUT, int BLK>
__global__ void __launch_bounds__(BLK)
aggregate(const float* __restrict__ h, const float* __restrict__ dinv,
          const int* __restrict__ rowptr, const int* __restrict__ col,
          float* __restrict__ out) {
    __shared__ int   sidx[64];
    __shared__ float sdv[64];
    int n  = blockIdx.x;
    int ch = threadIdx.x;
    int beg = rowptr[n], end = rowptr[n + 1];
    float dn  = dinv[n];
    float acc = 0.f;
    for (int base = beg; base < end; base += 64) {
        int c = min(64, end - base);
        __syncthreads();
        if (ch < c) {
            int s = col[base + ch];
            sidx[ch] = s;
            sdv[ch]  = dinv[s];
        }
        __syncthreads();
        if (ch < CIN) {
            #pragma unroll 4
            for (int j = 0; j < c; ++j)
                acc += sdv[j] * h[(long long)sidx[j] * CIN + ch];
        }
    }
    float self = (ch < CIN) ? h[(long long)n * CIN + ch] : 0.f;
    float r = dn * (acc + dn * self);
    if (ch < COUT) out[(long long)n * COUT + ch] = (ch < CIN) ? r : 0.f;
}

// ---------------- fp32 tiled GEMM: C = relu?(A@B + bias), A[M,K] B[K,N] ----------------
template <bool RELU>
__global__ void __launch_bounds__(256)
gemm_bias(const float* __restrict__ A, const float* __restrict__ B,
          const float* __restrict__ bias, float* __restrict__ C,
          int M, int K, int Nn) {
    constexpr int BM = 64, BN = 64, BK = 16;
    __shared__ float As[BK][BM + 4];   // [16][68]: 16B-aligned rows, conflict-benign
    __shared__ float Bs[BK][BN + 4];
    int tid = threadIdx.x;
    int tx = tid & 15, ty = tid >> 4;
    int bm = blockIdx.x * BM, bn = blockIdx.y * BN;
    float acc[4][4] = {};
    for (int kb = 0; kb < K; kb += BK) {
        {   // A tile 64x16 -> As[k][m] (transposed for broadcast reads)
            int li = tid * 4;
            int r = li >> 4, k = li & 15;
            float4 v = make_float4(0.f, 0.f, 0.f, 0.f);
            int row = bm + r;
            if (row < M) v = *(const float4*)(A + (long long)row * K + kb + k);
            As[k + 0][r] = v.x; As[k + 1][r] = v.y; As[k + 2][r] = v.z; As[k + 3][r] = v.w;
        }
        {   // B tile 16x64 -> Bs[k][n]
            int li = tid * 4;
            int r = li >> 6, c = li & 63;
            float4 v = *(const float4*)(B + (long long)(kb + r) * Nn + bn + c);
            *(float4*)&Bs[r][c] = v;
        }
        __syncthreads();
        #pragma unroll
        for (int kk = 0; kk < BK; ++kk) {
            float a[4], b[4];
            *(float4*)a = *(const float4*)&As[kk][ty * 4];
            *(float4*)b = *(const float4*)&Bs[kk][tx * 4];
            #pragma unroll
            for (int i = 0; i < 4; ++i)
                #pragma unroll
                for (int j = 0; j < 4; ++j)
                    acc[i][j] += a[i] * b[j];
        }
        __syncthreads();
    }
    float4 bv = *(const float4*)(bias + bn + tx * 4);
    #pragma unroll
    for (int i = 0; i < 4; ++i) {
        int row = bm + ty * 4 + i;
        if (row < M) {
            float4 o;
            o.x = acc[i][0] + bv.x; o.y = acc[i][1] + bv.y;
            o.z = acc[i][2] + bv.z; o.w = acc[i][3] + bv.w;
            if (RELU) {
                o.x = fmaxf(o.x, 0.f); o.y = fmaxf(o.y, 0.f);
                o.z = fmaxf(o.z, 0.f); o.w = fmaxf(o.w, 0.f);
            }
            *(float4*)(C + (long long)row * Nn + bn + tx * 4) = o;
        }
    }
}

// ---------------- layer-3 GEMM: hw3[n] = h2[n] @ W3 (256 -> 2), one wave/node ----------
__global__ void __launch_bounds__(64)
gemm3(const float* __restrict__ h2, const float* __restrict__ W3, float* __restrict__ hw3) {
    int n = blockIdx.x, l = threadIdx.x;
    float s0 = 0.f, s1 = 0.f;
    #pragma unroll
    for (int k = l; k < HID; k += 64) {
        float v = h2[(long long)n * HID + k];
        s0 += v * W3[k * 2 + 0];
        s1 += v * W3[k * 2 + 1];
    }
    #pragma unroll
    for (int off = 32; off > 0; off >>= 1) {
        s0 += __shfl_down(s0, off);
        s1 += __shfl_down(s1, off);
    }
    if (l == 0) {
        hw3[n * 2 + 0] = s0;
        hw3[n * 2 + 1] = s1;
    }
}

// ---------------- layer-3 aggregation (2 channels), thread per node ----------------
__global__ void agg3(const float* __restrict__ hw3, const float* __restrict__ dinv,
                     const int* __restrict__ rowptr, const int* __restrict__ col,
                     const float* __restrict__ b3, float* __restrict__ out) {
    int n = blockIdx.x * blockDim.x + threadIdx.x;
    if (n >= NN) return;
    float a0 = 0.f, a1 = 0.f;
    int beg = rowptr[n], end = rowptr[n + 1];
    for (int j = beg; j < end; ++j) {
        int s = col[j];
        float w = dinv[s];
        float2 v = ((const float2*)hw3)[s];
        a0 += w * v.x;
        a1 += w * v.y;
    }
    float dn = dinv[n];
    float2 sv = ((const float2*)hw3)[n];
    out[n * 2 + 0] = dn * (a0 + dn * sv.x) + b3[0];
    out[n * 2 + 1] = dn * (a1 + dn * sv.y) + b3[1];
}

// ---------------- clean pad_w1 (the one actually used) ----------------
__global__ void pad_w1_clean(const float* __restrict__ W1, float* __restrict__ W1p) {
    int i = blockIdx.x * 256 + threadIdx.x;   // over 128*256
    int k = i >> 8, c = i & 255;
    W1p[i] = (k < INC) ? W1[k * 256 + c] : 0.f;
}

extern "C" void kernel_launch(void* const* d_in, const int* in_sizes, int n_in,
                              void* d_out, int out_size, void* d_ws, size_t ws_size,
                              hipStream_t stream) {
    const float* x   = (const float*)d_in[0];
    const int*   ebf = (const int*)d_in[1];
    const float* W1  = (const float*)d_in[2];
    const float* b1  = (const float*)d_in[3];
    const float* W2  = (const float*)d_in[4];
    const float* b2  = (const float*)d_in[5];
    const float* W3  = (const float*)d_in[6];
    const float* b3  = (const float*)d_in[7];
    float* out = (float*)d_out;

    // workspace carve-up (256B aligned)
    char* ws = (char*)d_ws;
    size_t off = 0;
    auto carve = [&](size_t bytes) -> char* {
        char* p = ws + off;
        off += (bytes + 255) & ~(size_t)255;
        return p;
    };
    int*   flag    = (int*)  carve(256);
    int*   cnt     = (int*)  carve((size_t)NN * 4);
    float* dinv    = (float*)carve((size_t)NN * 4);
    int*   rowptr  = (int*)  carve((size_t)(NN + 1) * 4);
    int*   fillpos = (int*)  carve((size_t)NN * 4);
    int*   bsum    = (int*)  carve(256 * 4);
    int*   col     = (int*)  carve((size_t)NE * 4);
    float* W1p     = (float*)carve((size_t)K1P * HID * 4);
    float* agg1    = (float*)carve((size_t)NN * K1P * 4);
    float* h1      = (float*)carve((size_t)NN * HID * 4);
    float* agg2    = (float*)carve((size_t)NN * HID * 4);
    float* h2      = (float*)carve((size_t)NN * HID * 4);
    float* hw3     = (float*)carve((size_t)NN * OUTC * 4);
    (void)ws_size; (void)n_in; (void)in_sizes; (void)out_size;

    const int SCAN_G = (NN + 255) / 256;   // 196
    const int EG     = (NE + 255) / 256;   // 6250

    hipMemsetAsync(cnt, 0, (size_t)NN * 4, stream);
    detect_fmt<<<1, 64, 0, stream>>>(ebf, flag);
    deg_hist<<<EG, 256, 0, stream>>>(ebf, flag, cnt);
    dinv_kernel<<<SCAN_G, 256, 0, stream>>>(cnt, dinv);
    scan1<<<SCAN_G, 256, 0, stream>>>(cnt, rowptr, bsum);
    scan2<<<1, 256, 0, stream>>>(bsum, SCAN_G);
    scan3<<<SCAN_G, 256, 0, stream>>>(rowptr, bsum, fillpos);
    fill_csr<<<EG, 256, 0, stream>>>(ebf, flag, fillpos, col);
    pad_w1_clean<<<K1P, 256, 0, stream>>>(W1, W1p);

    // layer 1: aggregate x (116ch, pad to 128) then GEMM 128->256 + relu
    aggregate<INC, K1P, 128><<<NN, 128, 0, stream>>>(x, dinv, rowptr, col, agg1);
    {
        dim3 g((NN + 63) / 64, HID / 64);
        gemm_bias<true><<<g, 256, 0, stream>>>(agg1, W1p, b1, h1, NN, K1P, HID);
    }
    // layer 2: aggregate h1 (256ch) then GEMM 256->256 + relu
    aggregate<HID, HID, 256><<<NN, 256, 0, stream>>>(h1, dinv, rowptr, col, agg2);
    {
        dim3 g((NN + 63) / 64, HID / 64);
        gemm_bias<true><<<g, 256, 0, stream>>>(agg2, W2, b2, h2, NN, HID, HID);
    }
    // layer 3: GEMM 256->2 first, then 2-channel aggregation + bias
    gemm3<<<NN, 64, 0, stream>>>(h2, W3, hw3);
    agg3<<<SCAN_G, 256, 0, stream>>>(hw3, dinv, rowptr, col, b3, out);
}

// Round 2
// 748.812 us; speedup vs baseline: 1.0764x; 1.0764x over previous
//
#include <hip/hip_runtime.h>
#include <hip/hip_bf16.h>
#include <stdint.h>

#define NN 50000
#define NE 1600000
#define INC 116
#define K1P 128     // padded K for layer-1 GEMM
#define HID 256
#define OUTC 2

typedef float f32x4 __attribute__((ext_vector_type(4)));
typedef short s16x8 __attribute__((ext_vector_type(8)));

// bf16 helpers (round-to-nearest-even), bit-level to avoid type friction
__device__ __forceinline__ ushort f2bf(float v) {
    uint32_t u = __float_as_uint(v);
    uint32_t r = (u + 0x7FFFu + ((u >> 16) & 1u)) >> 16;
    return (ushort)r;
}
__device__ __forceinline__ float bf2f(ushort b) {
    return __uint_as_float(((uint32_t)b) << 16);
}

// ---------------- edge-index format hedge (int32 vs int64) ----------------
__global__ void detect_fmt(const int* __restrict__ ebuf, int* __restrict__ flag) {
    int v = ebuf[2 * threadIdx.x + 1];
    unsigned long long b = __ballot(v != 0);
    if (threadIdx.x == 0) flag[0] = (b == 0ULL) ? 1 : 0;
}

__device__ __forceinline__ int edge_at(const int* __restrict__ ebuf, int is64, int idx) {
    return is64 ? ebuf[2 * idx] : ebuf[idx];
}

// ---------------- degree histogram ----------------
__global__ void deg_hist(const int* __restrict__ ebuf, const int* __restrict__ flag,
                         int* __restrict__ cnt) {
    int e = blockIdx.x * blockDim.x + threadIdx.x;
    if (e >= NE) return;
    int is64 = flag[0];
    int d = edge_at(ebuf, is64, NE + e);
    atomicAdd(&cnt[d], 1);
}

__global__ void dinv_kernel(const int* __restrict__ cnt, float* __restrict__ dinv) {
    int n = blockIdx.x * blockDim.x + threadIdx.x;
    if (n < NN) dinv[n] = rsqrtf((float)cnt[n] + 1.0f);
}

// ---------------- prefix scan ----------------
__global__ void scan1(const int* __restrict__ cnt, int* __restrict__ rowptr,
                      int* __restrict__ bsum) {
    __shared__ int s[256];
    int tid = threadIdx.x;
    int i = blockIdx.x * 256 + tid;
    int v = (i < NN) ? cnt[i] : 0;
    s[tid] = v;
    __syncthreads();
    for (int off = 1; off < 256; off <<= 1) {
        int t = (tid >= off) ? s[tid - off] : 0;
        __syncthreads();
        s[tid] += t;
        __syncthreads();
    }
    if (i < NN) rowptr[i] = s[tid] - v;
    if (tid == 255) bsum[blockIdx.x] = s[255];
}

__global__ void scan2(int* __restrict__ bsum, int nblocks) {
    __shared__ int s[256];
    int tid = threadIdx.x;
    int v = (tid < nblocks) ? bsum[tid] : 0;
    s[tid] = v;
    __syncthreads();
    for (int off = 1; off < 256; off <<= 1) {
        int t = (tid >= off) ? s[tid - off] : 0;
        __syncthreads();
        s[tid] += t;
        __syncthreads();
    }
    if (tid < nblocks) bsum[tid] = s[tid] - v;
}

__global__ void scan3(int* __restrict__ rowptr, const int* __restrict__ bsum,
                      int* __restrict__ fillpos) {
    int i = blockIdx.x * 256 + threadIdx.x;
    if (i < NN) {
        int r = rowptr[i] + bsum[blockIdx.x];
        rowptr[i] = r;
        fillpos[i] = r;
        if (i == NN - 1) rowptr[NN] = NE;
    }
}

__global__ void fill_csr(const int* __restrict__ ebuf, const int* __restrict__ flag,
                         int* __restrict__ fillpos, int* __restrict__ col) {
    int e = blockIdx.x * blockDim.x + threadIdx.x;
    if (e >= NE) return;
    int is64 = flag[0];
    int s = edge_at(ebuf, is64, e);
    int d = edge_at(ebuf, is64, NE + e);
    int p = atomicAdd(&fillpos[d], 1);
    col[p] = s;
}

// ---------------- weight decompose + transpose ----------------
// W1 [116][256] -> W1t hi/lo [256][128] (k padded with zeros)
__global__ void decomp_w1(const float* __restrict__ W, ushort* __restrict__ hi,
                          ushort* __restrict__ lo) {
    int i = blockIdx.x * 256 + threadIdx.x;   // 256*128
    int n = i >> 7, k = i & 127;
    float v = (k < INC) ? W[k * HID + n] : 0.f;
    ushort h = f2bf(v);
    ushort l = f2bf(v - bf2f(h));
    hi[n * K1P + k] = h;
    lo[n * K1P + k] = l;
}

// W2 [256][256] -> W2t hi/lo [256][256]
__global__ void decomp_w2(const float* __restrict__ W, ushort* __restrict__ hi,
                          ushort* __restrict__ lo) {
    int i = blockIdx.x * 256 + threadIdx.x;   // 256*256
    int n = i >> 8, k = i & 255;
    float v = W[k * HID + n];
    ushort h = f2bf(v);
    ushort l = f2bf(v - bf2f(h));
    hi[n * HID + k] = h;
    lo[n * HID + k] = l;
}

// ---------------- pull aggregation, float4 gathers, hi/lo bf16 output --------
// out[n] = dinv[n]*(sum_s dinv[s]*h[s] + dinv[n]*h[n]); written as bf16 hi+lo
// SR: input row stride (floats). CV4: float4s per input row. NPART participants
// of LPW lanes each (NPART*LPW==256). COUT: output row stride (bf16), COUTV4*4.
template <int SR, int CV4, int NPART, int LPW, int COUTV4, int COUT>
__global__ void __launch_bounds__(256)
aggregate4(const float* __restrict__ h, const float* __restrict__ dinv,
           const int* __restrict__ rowptr, const int* __restrict__ col,
           ushort* __restrict__ ohi, ushort* __restrict__ olo) {
    __shared__ float red[NPART][CV4][4];
    int n = blockIdx.x;
    int tid = threadIdx.x;
    int pid = tid / LPW;
    int lane = tid % LPW;
    int beg = rowptr[n], end = rowptr[n + 1];
    if (lane < CV4) {
        float ax = 0.f, ay = 0.f, az = 0.f, aw = 0.f;
        const float* hp = h + (size_t)lane * 4;
        int j = beg + pid;
        for (; j + NPART < end; j += 2 * NPART) {
            int s0 = col[j], s1 = col[j + NPART];
            float w0 = dinv[s0], w1 = dinv[s1];
            float4 v0 = *(const float4*)(hp + (size_t)s0 * SR);
            float4 v1 = *(const float4*)(hp + (size_t)s1 * SR);
            ax += w0 * v0.x + w1 * v1.x;
            ay += w0 * v0.y + w1 * v1.y;
            az += w0 * v0.z + w1 * v1.z;
            aw += w0 * v0.w + w1 * v1.w;
        }
        if (j < end) {
            int s0 = col[j];
            float w0 = dinv[s0];
            float4 v0 = *(const float4*)(hp + (size_t)s0 * SR);
            ax += w0 * v0.x; ay += w0 * v0.y; az += w0 * v0.z; aw += w0 * v0.w;
        }
        red[pid][lane][0] = ax; red[pid][lane][1] = ay;
        red[pid][lane][2] = az; red[pid][lane][3] = aw;
    }
    __syncthreads();
    if (tid < COUTV4) {
        float rx = 0.f, ry = 0.f, rz = 0.f, rw = 0.f;
        if (tid < CV4) {
            #pragma unroll
            for (int p = 0; p < NPART; ++p) {
                rx += red[p][tid][0]; ry += red[p][tid][1];
                rz += red[p][tid][2]; rw += red[p][tid][3];
            }
            float dn = dinv[n];
            float4 sv = *(const float4*)(h + (size_t)n * SR + tid * 4);
            rx = dn * (rx + dn * sv.x);
            ry = dn * (ry + dn * sv.y);
            rz = dn * (rz + dn * sv.z);
            rw = dn * (rw + dn * sv.w);
        }
        ushort4 uh, ul;
        uh.x = f2bf(rx); ul.x = f2bf(rx - bf2f(uh.x));
        uh.y = f2bf(ry); ul.y = f2bf(ry - bf2f(uh.y));
        uh.z = f2bf(rz); ul.z = f2bf(rz - bf2f(uh.z));
        uh.w = f2bf(rw); ul.w = f2bf(rw - bf2f(uh.w));
        *(ushort4*)(ohi + (size_t)n * COUT + tid * 4) = uh;
        *(ushort4*)(olo + (size_t)n * COUT + tid * 4) = ul;
    }
}

// ---------------- MFMA GEMM, split-bf16 fp32 emulation -----------------------
// C[m][n] = relu?( sum_k A[m][k]*Bt[n][k] + bias[n] )
// A given as hi/lo bf16 [M][K]; Bt as hi/lo bf16 [N][K] (pre-transposed).
// acc += Ahi*Bhi + Ahi*Blo + Alo*Bhi  (lo*lo dropped, ~2^-18 relative)
template <bool RELU>
__global__ void __launch_bounds__(256)
gemm_mfma(const ushort* __restrict__ Ahi, const ushort* __restrict__ Alo,
          const ushort* __restrict__ Bhi, const ushort* __restrict__ Blo,
          const float* __restrict__ bias, float* __restrict__ C,
          int M, int K, int Nn) {
    constexpr int BM = 128, BN = 128, BK = 32, LDK = BK + 8;  // +8 shorts: bank spread
    __shared__ ushort sAh[BM * LDK], sAl[BM * LDK];
    __shared__ ushort sBh[BN * LDK], sBl[BN * LDK];
    int tid = threadIdx.x;
    int w = tid >> 6, l = tid & 63;
    int wr = w >> 1, wc = w & 1;          // wave -> 64x64 quadrant
    int bm = blockIdx.x * BM, bn = blockIdx.y * BN;
    int l15 = l & 15, kg = l >> 4;
    f32x4 zero = {0.f, 0.f, 0.f, 0.f};
    f32x4 acc[4][4];
    #pragma unroll
    for (int i = 0; i < 4; ++i)
        #pragma unroll
        for (int j = 0; j < 4; ++j) acc[i][j] = zero;

    for (int kb = 0; kb < K; kb += BK) {
        // stage 4 tiles: each 128 rows x 32 shorts, 512 chunks of 8 shorts (16B)
        #pragma unroll
        for (int it = 0; it < 2; ++it) {
            int c = tid + it * 256;
            int row = c >> 2, kp = (c & 3) * 8;
            int ar = bm + row;
            float4 z4 = make_float4(0.f, 0.f, 0.f, 0.f);
            float4 avh = z4, avl = z4;
            if (ar < M) {
                avh = *(const float4*)(Ahi + (size_t)ar * K + kb + kp);
                avl = *(const float4*)(Alo + (size_t)ar * K + kb + kp);
            }
            *(float4*)&sAh[row * LDK + kp] = avh;
            *(float4*)&sAl[row * LDK + kp] = avl;
            int br = bn + row;  // always < Nn (Nn=256)
            float4 bvh = *(const float4*)(Bhi + (size_t)br * K + kb + kp);
            float4 bvl = *(const float4*)(Blo + (size_t)br * K + kb + kp);
            *(float4*)&sBh[row * LDK + kp] = bvh;
            *(float4*)&sBl[row * LDK + kp] = bvl;
        }
        __syncthreads();
        s16x8 ah[4], al[4], bh[4], bl[4];
        #pragma unroll
        for (int i = 0; i < 4; ++i) {
            int arow = wr * 64 + i * 16 + l15;
            ah[i] = *(const s16x8*)&sAh[arow * LDK + kg * 8];
            al[i] = *(const s16x8*)&sAl[arow * LDK + kg * 8];
            int brow = wc * 64 + i * 16 + l15;
            bh[i] = *(const s16x8*)&sBh[brow * LDK + kg * 8];
            bl[i] = *(const s16x8*)&sBl[brow * LDK + kg * 8];
        }
        #pragma unroll
        for (int i = 0; i < 4; ++i)
            #pragma unroll
            for (int j = 0; j < 4; ++j) {
                acc[i][j] = __builtin_amdgcn_mfma_f32_16x16x32_bf16(ah[i], bh[j], acc[i][j], 0, 0, 0);
                acc[i][j] = __builtin_amdgcn_mfma_f32_16x16x32_bf16(ah[i], bl[j], acc[i][j], 0, 0, 0);
                acc[i][j] = __builtin_amdgcn_mfma_f32_16x16x32_bf16(al[i], bh[j], acc[i][j], 0, 0, 0);
            }
        __syncthreads();
    }
    // epilogue: C/D layout col = l&15, row = (l>>4)*4 + r
    #pragma unroll
    for (int j = 0; j < 4; ++j) {
        int cn = bn + wc * 64 + j * 16 + l15;
        float bv = bias[cn];
        #pragma unroll
        for (int i = 0; i < 4; ++i) {
            int rbase = bm + wr * 64 + i * 16 + kg * 4;
            #pragma unroll
            for (int r = 0; r < 4; ++r) {
                int rm = rbase + r;
                if (rm < M) {
                    float v = acc[i][j][r] + bv;
                    if (RELU) v = fmaxf(v, 0.f);
                    C[(size_t)rm * Nn + cn] = v;
                }
            }
        }
    }
}

// ---------------- layer-3 GEMM: 256 -> 2, one wave/node ----------------------
__global__ void __launch_bounds__(64)
gemm3(const float* __restrict__ h2, const float* __restrict__ W3, float* __restrict__ hw3) {
    int n = blockIdx.x, l = threadIdx.x;
    float s0 = 0.f, s1 = 0.f;
    #pragma unroll
    for (int k = l; k < HID; k += 64) {
        float v = h2[(size_t)n * HID + k];
        s0 += v * W3[k * 2 + 0];
        s1 += v * W3[k * 2 + 1];
    }
    #pragma unroll
    for (int off = 32; off > 0; off >>= 1) {
        s0 += __shfl_down(s0, off);
        s1 += __shfl_down(s1, off);
    }
    if (l == 0) {
        hw3[n * 2 + 0] = s0;
        hw3[n * 2 + 1] = s1;
    }
}

// ---------------- layer-3 aggregation (2 channels) ---------------------------
__global__ void agg3(const float* __restrict__ hw3, const float* __restrict__ dinv,
                     const int* __restrict__ rowptr, const int* __restrict__ col,
                     const float* __restrict__ b3, float* __restrict__ out) {
    int n = blockIdx.x * blockDim.x + threadIdx.x;
    if (n >= NN) return;
    float a0 = 0.f, a1 = 0.f;
    int beg = rowptr[n], end = rowptr[n + 1];
    for (int j = beg; j < end; ++j) {
        int s = col[j];
        float w = dinv[s];
        float2 v = ((const float2*)hw3)[s];
        a0 += w * v.x;
        a1 += w * v.y;
    }
    float dn = dinv[n];
    float2 sv = ((const float2*)hw3)[n];
    out[n * 2 + 0] = dn * (a0 + dn * sv.x) + b3[0];
    out[n * 2 + 1] = dn * (a1 + dn * sv.y) + b3[1];
}

extern "C" void kernel_launch(void* const* d_in, const int* in_sizes, int n_in,
                              void* d_out, int out_size, void* d_ws, size_t ws_size,
                              hipStream_t stream) {
    const float* x   = (const float*)d_in[0];
    const int*   ebf = (const int*)d_in[1];
    const float* W1  = (const float*)d_in[2];
    const float* b1  = (const float*)d_in[3];
    const float* W2  = (const float*)d_in[4];
    const float* b2  = (const float*)d_in[5];
    const float* W3  = (const float*)d_in[6];
    const float* b3  = (const float*)d_in[7];
    float* out = (float*)d_out;

    char* ws = (char*)d_ws;
    size_t off = 0;
    auto carve = [&](size_t bytes) -> char* {
        char* p = ws + off;
        off += (bytes + 255) & ~(size_t)255;
        return p;
    };
    int*    flag   = (int*)   carve(256);
    int*    cnt    = (int*)   carve((size_t)NN * 4);
    float*  dinv   = (float*) carve((size_t)NN * 4);
    int*    rowptr = (int*)   carve((size_t)(NN + 1) * 4);
    int*    fillpos= (int*)   carve((size_t)NN * 4);
    int*    bsum   = (int*)   carve(256 * 4);
    int*    col    = (int*)   carve((size_t)NE * 4);
    ushort* W1thi  = (ushort*)carve((size_t)HID * K1P * 2);
    ushort* W1tlo  = (ushort*)carve((size_t)HID * K1P * 2);
    ushort* W2thi  = (ushort*)carve((size_t)HID * HID * 2);
    ushort* W2tlo  = (ushort*)carve((size_t)HID * HID * 2);
    ushort* a1hi   = (ushort*)carve((size_t)NN * K1P * 2);
    ushort* a1lo   = (ushort*)carve((size_t)NN * K1P * 2);
    float*  h1     = (float*) carve((size_t)NN * HID * 4);
    ushort* a2hi   = (ushort*)carve((size_t)NN * HID * 2);
    ushort* a2lo   = (ushort*)carve((size_t)NN * HID * 2);
    float*  h2     = (float*) carve((size_t)NN * HID * 4);
    float*  hw3    = (float*) carve((size_t)NN * OUTC * 4);
    (void)ws_size; (void)n_in; (void)in_sizes; (void)out_size;

    const int SCAN_G = (NN + 255) / 256;
    const int EG     = (NE + 255) / 256;

    hipMemsetAsync(cnt, 0, (size_t)NN * 4, stream);
    detect_fmt<<<1, 64, 0, stream>>>(ebf, flag);
    deg_hist<<<EG, 256, 0, stream>>>(ebf, flag, cnt);
    dinv_kernel<<<SCAN_G, 256, 0, stream>>>(cnt, dinv);
    scan1<<<SCAN_G, 256, 0, stream>>>(cnt, rowptr, bsum);
    scan2<<<1, 256, 0, stream>>>(bsum, SCAN_G);
    scan3<<<SCAN_G, 256, 0, stream>>>(rowptr, bsum, fillpos);
    fill_csr<<<EG, 256, 0, stream>>>(ebf, flag, fillpos, col);
    decomp_w1<<<(HID * K1P) / 256, 256, 0, stream>>>(W1, W1thi, W1tlo);
    decomp_w2<<<(HID * HID) / 256, 256, 0, stream>>>(W2, W2thi, W2tlo);

    // layer 1: aggregate x (116ch) -> hi/lo bf16 [N][128], then MFMA 128->256 + relu
    aggregate4<INC, 29, 8, 32, 32, K1P><<<NN, 256, 0, stream>>>(x, dinv, rowptr, col, a1hi, a1lo);
    {
        dim3 g((NN + 127) / 128, HID / 128);
        gemm_mfma<true><<<g, 256, 0, stream>>>(a1hi, a1lo, W1thi, W1tlo, b1, h1, NN, K1P, HID);
    }
    // layer 2: aggregate h1 (256ch) -> hi/lo bf16, then MFMA 256->256 + relu
    aggregate4<HID, 64, 4, 64, 64, HID><<<NN, 256, 0, stream>>>(h1, dinv, rowptr, col, a2hi, a2lo);
    {
        dim3 g((NN + 127) / 128, HID / 128);
        gemm_mfma<true><<<g, 256, 0, stream>>>(a2hi, a2lo, W2thi, W2tlo, b2, h2, NN, HID, HID);
    }
    // layer 3: GEMM 256->2 first, then 2-channel aggregation + bias
    gemm3<<<NN, 64, 0, stream>>>(h2, W3, hw3);
    agg3<<<SCAN_G, 256, 0, stream>>>(hw3, dinv, rowptr, col, b3, out);
}

// Round 3
// 588.458 us; speedup vs baseline: 1.3697x; 1.2725x over previous
//
#include <hip/hip_runtime.h>
#include <hip/hip_bf16.h>
#include <stdint.h>

#define NN 50000
#define NE 1600000
#define INC 116
#define XBP 120     // bf16-padded x row stride (15 x 16B chunks)
#define K1P 128     // padded K for layer-1 GEMM
#define HID 256
#define OUTC 2

typedef float f32x4 __attribute__((ext_vector_type(4)));
typedef short s16x8 __attribute__((ext_vector_type(8)));

// bf16 helpers (round-to-nearest-even), bit-level
__device__ __forceinline__ ushort f2bf(float v) {
    uint32_t u = __float_as_uint(v);
    return (ushort)((u + 0x7FFFu + ((u >> 16) & 1u)) >> 16);
}
__device__ __forceinline__ float bf2f(ushort b) {
    return __uint_as_float(((uint32_t)b) << 16);
}
__device__ __forceinline__ float bflo(uint32_t u) { return __uint_as_float(u << 16); }
__device__ __forceinline__ float bfhi(uint32_t u) { return __uint_as_float(u & 0xFFFF0000u); }

// ---------------- edge-index format hedge (int32 vs int64) ----------------
__global__ void detect_fmt(const int* __restrict__ ebuf, int* __restrict__ flag) {
    int v = ebuf[2 * threadIdx.x + 1];
    unsigned long long b = __ballot(v != 0);
    if (threadIdx.x == 0) flag[0] = (b == 0ULL) ? 1 : 0;
}

__device__ __forceinline__ int edge_at(const int* __restrict__ ebuf, int is64, int idx) {
    return is64 ? ebuf[2 * idx] : ebuf[idx];
}

// ---------------- degree histogram ----------------
__global__ void deg_hist(const int* __restrict__ ebuf, const int* __restrict__ flag,
                         int* __restrict__ cnt) {
    int e = blockIdx.x * blockDim.x + threadIdx.x;
    if (e >= NE) return;
    int is64 = flag[0];
    int d = edge_at(ebuf, is64, NE + e);
    atomicAdd(&cnt[d], 1);
}

__global__ void dinv_kernel(const int* __restrict__ cnt, float* __restrict__ dinv) {
    int n = blockIdx.x * blockDim.x + threadIdx.x;
    if (n < NN) dinv[n] = rsqrtf((float)cnt[n] + 1.0f);
}

// ---------------- prefix scan ----------------
__global__ void scan1(const int* __restrict__ cnt, int* __restrict__ rowptr,
                      int* __restrict__ bsum) {
    __shared__ int s[256];
    int tid = threadIdx.x;
    int i = blockIdx.x * 256 + tid;
    int v = (i < NN) ? cnt[i] : 0;
    s[tid] = v;
    __syncthreads();
    for (int off = 1; off < 256; off <<= 1) {
        int t = (tid >= off) ? s[tid - off] : 0;
        __syncthreads();
        s[tid] += t;
        __syncthreads();
    }
    if (i < NN) rowptr[i] = s[tid] - v;
    if (tid == 255) bsum[blockIdx.x] = s[255];
}

__global__ void scan2(int* __restrict__ bsum, int nblocks) {
    __shared__ int s[256];
    int tid = threadIdx.x;
    int v = (tid < nblocks) ? bsum[tid] : 0;
    s[tid] = v;
    __syncthreads();
    for (int off = 1; off < 256; off <<= 1) {
        int t = (tid >= off) ? s[tid - off] : 0;
        __syncthreads();
        s[tid] += t;
        __syncthreads();
    }
    if (tid < nblocks) bsum[tid] = s[tid] - v;
}

__global__ void scan3(int* __restrict__ rowptr, const int* __restrict__ bsum,
                      int* __restrict__ fillpos) {
    int i = blockIdx.x * 256 + threadIdx.x;
    if (i < NN) {
        int r = rowptr[i] + bsum[blockIdx.x];
        rowptr[i] = r;
        fillpos[i] = r;
        if (i == NN - 1) rowptr[NN] = NE;
    }
}

__global__ void fill_csr(const int* __restrict__ ebuf, const int* __restrict__ flag,
                         int* __restrict__ fillpos, int* __restrict__ col) {
    int e = blockIdx.x * blockDim.x + threadIdx.x;
    if (e >= NE) return;
    int is64 = flag[0];
    int s = edge_at(ebuf, is64, e);
    int d = edge_at(ebuf, is64, NE + e);
    int p = atomicAdd(&fillpos[d], 1);
    col[p] = s;
}

// ---------------- x -> bf16 padded [NN][120] ----------------
__global__ void conv_x(const float* __restrict__ x, ushort* __restrict__ xb) {
    int i = blockIdx.x * 256 + threadIdx.x;
    if (i >= NN * XBP) return;
    int n = i / XBP, c = i - n * XBP;
    xb[i] = (c < INC) ? f2bf(x[(size_t)n * INC + c]) : (ushort)0;
}

// ---------------- weight decompose + transpose ----------------
__global__ void decomp_w1(const float* __restrict__ W, ushort* __restrict__ hi,
                          ushort* __restrict__ lo) {
    int i = blockIdx.x * 256 + threadIdx.x;   // 256*128
    int n = i >> 7, k = i & 127;
    float v = (k < INC) ? W[k * HID + n] : 0.f;
    ushort h = f2bf(v);
    hi[n * K1P + k] = h;
    lo[n * K1P + k] = f2bf(v - bf2f(h));
}

__global__ void decomp_w2(const float* __restrict__ W, ushort* __restrict__ hi,
                          ushort* __restrict__ lo) {
    int i = blockIdx.x * 256 + threadIdx.x;   // 256*256
    int n = i >> 8, k = i & 255;
    float v = W[k * HID + n];
    ushort h = f2bf(v);
    hi[n * HID + k] = h;
    lo[n * HID + k] = f2bf(v - bf2f(h));
}

// ---------------- layer-1 aggregate: gather bf16 x [NN][120] ----------------
// out[n] = dinv[n]*(sum_s dinv[s]*x[s] + dinv[n]*x[n]); self term from fp32 x.
// 16 groups x 16 lanes; lane c<15 handles 16B chunk c (8 channels).
__global__ void __launch_bounds__(256)
agg1b(const ushort* __restrict__ xb, const float* __restrict__ x,
      const float* __restrict__ dinv, const int* __restrict__ rowptr,
      const int* __restrict__ col, ushort* __restrict__ ohi, ushort* __restrict__ olo) {
    __shared__ float red[16][15][8];
    int n = blockIdx.x, tid = threadIdx.x;
    int g = tid >> 4, c = tid & 15;
    int beg = rowptr[n], end = rowptr[n + 1];
    if (c < 15) {
        float a0=0.f,a1=0.f,a2=0.f,a3=0.f,a4=0.f,a5=0.f,a6=0.f,a7=0.f;
        const ushort* hc = xb + c * 8;
        int j = beg + g;
        for (; j + 16 < end; j += 32) {
            int s0 = col[j], s1 = col[j + 16];
            float w0 = dinv[s0], w1 = dinv[s1];
            uint4 u0 = *(const uint4*)(hc + (size_t)s0 * XBP);
            uint4 u1 = *(const uint4*)(hc + (size_t)s1 * XBP);
            a0 += w0 * bflo(u0.x) + w1 * bflo(u1.x);
            a1 += w0 * bfhi(u0.x) + w1 * bfhi(u1.x);
            a2 += w0 * bflo(u0.y) + w1 * bflo(u1.y);
            a3 += w0 * bfhi(u0.y) + w1 * bfhi(u1.y);
            a4 += w0 * bflo(u0.z) + w1 * bflo(u1.z);
            a5 += w0 * bfhi(u0.z) + w1 * bfhi(u1.z);
            a6 += w0 * bflo(u0.w) + w1 * bflo(u1.w);
            a7 += w0 * bfhi(u0.w) + w1 * bfhi(u1.w);
        }
        if (j < end) {
            int s0 = col[j];
            float w0 = dinv[s0];
            uint4 u0 = *(const uint4*)(hc + (size_t)s0 * XBP);
            a0 += w0 * bflo(u0.x); a1 += w0 * bfhi(u0.x);
            a2 += w0 * bflo(u0.y); a3 += w0 * bfhi(u0.y);
            a4 += w0 * bflo(u0.z); a5 += w0 * bfhi(u0.z);
            a6 += w0 * bflo(u0.w); a7 += w0 * bfhi(u0.w);
        }
        red[g][c][0]=a0; red[g][c][1]=a1; red[g][c][2]=a2; red[g][c][3]=a3;
        red[g][c][4]=a4; red[g][c][5]=a5; red[g][c][6]=a6; red[g][c][7]=a7;
    }
    __syncthreads();
    int t = tid;
    if (t < K1P) {
        float r = 0.f;
        if (t < XBP) {
            float s = 0.f;
            #pragma unroll
            for (int gg = 0; gg < 16; ++gg) s += red[gg][t >> 3][t & 7];
            float self = (t < INC) ? x[(size_t)n * INC + t] : 0.f;
            float dn = dinv[n];
            r = dn * (s + dn * self);
        }
        ushort h = f2bf(r);
        ohi[(size_t)n * K1P + t] = h;
        olo[(size_t)n * K1P + t] = f2bf(r - bf2f(h));
    }
}

// ---------------- layer-2 aggregate: gather bf16 h1 [NN][256] ----------------
// 8 groups x 32 lanes; lane c handles 16B chunk c (8 channels).
__global__ void __launch_bounds__(256)
agg2b(const ushort* __restrict__ hb, const float* __restrict__ dinv,
      const int* __restrict__ rowptr, const int* __restrict__ col,
      ushort* __restrict__ ohi, ushort* __restrict__ olo) {
    __shared__ float red[8][32][8];
    int n = blockIdx.x, tid = threadIdx.x;
    int g = tid >> 5, c = tid & 31;
    int beg = rowptr[n], end = rowptr[n + 1];
    {
        float a0=0.f,a1=0.f,a2=0.f,a3=0.f,a4=0.f,a5=0.f,a6=0.f,a7=0.f;
        const ushort* hc = hb + c * 8;
        int j = beg + g;
        for (; j + 8 < end; j += 16) {
            int s0 = col[j], s1 = col[j + 8];
            float w0 = dinv[s0], w1 = dinv[s1];
            uint4 u0 = *(const uint4*)(hc + (size_t)s0 * HID);
            uint4 u1 = *(const uint4*)(hc + (size_t)s1 * HID);
            a0 += w0 * bflo(u0.x) + w1 * bflo(u1.x);
            a1 += w0 * bfhi(u0.x) + w1 * bfhi(u1.x);
            a2 += w0 * bflo(u0.y) + w1 * bflo(u1.y);
            a3 += w0 * bfhi(u0.y) + w1 * bfhi(u1.y);
            a4 += w0 * bflo(u0.z) + w1 * bflo(u1.z);
            a5 += w0 * bfhi(u0.z) + w1 * bfhi(u1.z);
            a6 += w0 * bflo(u0.w) + w1 * bflo(u1.w);
            a7 += w0 * bfhi(u0.w) + w1 * bfhi(u1.w);
        }
        if (j < end) {
            int s0 = col[j];
            float w0 = dinv[s0];
            uint4 u0 = *(const uint4*)(hc + (size_t)s0 * HID);
            a0 += w0 * bflo(u0.x); a1 += w0 * bfhi(u0.x);
            a2 += w0 * bflo(u0.y); a3 += w0 * bfhi(u0.y);
            a4 += w0 * bflo(u0.z); a5 += w0 * bfhi(u0.z);
            a6 += w0 * bflo(u0.w); a7 += w0 * bfhi(u0.w);
        }
        red[g][c][0]=a0; red[g][c][1]=a1; red[g][c][2]=a2; red[g][c][3]=a3;
        red[g][c][4]=a4; red[g][c][5]=a5; red[g][c][6]=a6; red[g][c][7]=a7;
    }
    __syncthreads();
    int t = tid;
    float s = 0.f;
    #pragma unroll
    for (int gg = 0; gg < 8; ++gg) s += red[gg][t >> 3][t & 7];
    float dn = dinv[n];
    float self = bf2f(hb[(size_t)n * HID + t]);
    float r = dn * (s + dn * self);
    ushort h = f2bf(r);
    ohi[(size_t)n * HID + t] = h;
    olo[(size_t)n * HID + t] = f2bf(r - bf2f(h));
}

// ---------------- MFMA GEMM, split-bf16 fp32 emulation -----------------------
// MODE 1: C = bf16( relu(A@Bt + bias) )           (layer 1 -> h1b)
// MODE 2: fused layer-3: v = relu(A@Bt + bias); atomicAdd hw3[row] += v @ W3
template <int MODE>
__global__ void __launch_bounds__(256)
gemm_mfma(const ushort* __restrict__ Ahi, const ushort* __restrict__ Alo,
          const ushort* __restrict__ Bhi, const ushort* __restrict__ Blo,
          const float* __restrict__ bias, ushort* __restrict__ Cb,
          const float* __restrict__ W3, float* __restrict__ hw3,
          int M, int K, int Nn) {
    constexpr int BM = 128, BN = 128, BK = 32, LDK = BK + 8;
    __shared__ ushort sAh[BM * LDK], sAl[BM * LDK];
    __shared__ ushort sBh[BN * LDK], sBl[BN * LDK];
    int tid = threadIdx.x;
    int w = tid >> 6, l = tid & 63;
    int wr = w >> 1, wc = w & 1;
    int bm = blockIdx.x * BM, bn = blockIdx.y * BN;
    int l15 = l & 15, kg = l >> 4;
    f32x4 zero = {0.f, 0.f, 0.f, 0.f};
    f32x4 acc[4][4];
    #pragma unroll
    for (int i = 0; i < 4; ++i)
        #pragma unroll
        for (int j = 0; j < 4; ++j) acc[i][j] = zero;

    for (int kb = 0; kb < K; kb += BK) {
        #pragma unroll
        for (int it = 0; it < 2; ++it) {
            int cc = tid + it * 256;
            int row = cc >> 2, kp = (cc & 3) * 8;
            int ar = bm + row;
            float4 z4 = make_float4(0.f, 0.f, 0.f, 0.f);
            float4 avh = z4, avl = z4;
            if (ar < M) {
                avh = *(const float4*)(Ahi + (size_t)ar * K + kb + kp);
                avl = *(const float4*)(Alo + (size_t)ar * K + kb + kp);
            }
            *(float4*)&sAh[row * LDK + kp] = avh;
            *(float4*)&sAl[row * LDK + kp] = avl;
            int br = bn + row;  // Nn == 256 always covers
            float4 bvh = *(const float4*)(Bhi + (size_t)br * K + kb + kp);
            float4 bvl = *(const float4*)(Blo + (size_t)br * K + kb + kp);
            *(float4*)&sBh[row * LDK + kp] = bvh;
            *(float4*)&sBl[row * LDK + kp] = bvl;
        }
        __syncthreads();
        s16x8 ah[4], al[4], bh[4], bl[4];
        #pragma unroll
        for (int i = 0; i < 4; ++i) {
            int arow = wr * 64 + i * 16 + l15;
            ah[i] = *(const s16x8*)&sAh[arow * LDK + kg * 8];
            al[i] = *(const s16x8*)&sAl[arow * LDK + kg * 8];
            int brow = wc * 64 + i * 16 + l15;
            bh[i] = *(const s16x8*)&sBh[brow * LDK + kg * 8];
            bl[i] = *(const s16x8*)&sBl[brow * LDK + kg * 8];
        }
        #pragma unroll
        for (int i = 0; i < 4; ++i)
            #pragma unroll
            for (int j = 0; j < 4; ++j) {
                acc[i][j] = __builtin_amdgcn_mfma_f32_16x16x32_bf16(ah[i], bh[j], acc[i][j], 0, 0, 0);
                acc[i][j] = __builtin_amdgcn_mfma_f32_16x16x32_bf16(ah[i], bl[j], acc[i][j], 0, 0, 0);
                acc[i][j] = __builtin_amdgcn_mfma_f32_16x16x32_bf16(al[i], bh[j], acc[i][j], 0, 0, 0);
            }
        __syncthreads();
    }
    // C/D layout: col = l&15, row = (l>>4)*4 + r
    if (MODE == 1) {
        #pragma unroll
        for (int j = 0; j < 4; ++j) {
            int cn = bn + wc * 64 + j * 16 + l15;
            float bv = bias[cn];
            #pragma unroll
            for (int i = 0; i < 4; ++i) {
                int rbase = bm + wr * 64 + i * 16 + kg * 4;
                #pragma unroll
                for (int r = 0; r < 4; ++r) {
                    int rm = rbase + r;
                    if (rm < M) {
                        float v = fmaxf(acc[i][j][r] + bv, 0.f);
                        Cb[(size_t)rm * Nn + cn] = f2bf(v);
                    }
                }
            }
        }
    } else {
        float p0[4][4], p1[4][4];
        #pragma unroll
        for (int i = 0; i < 4; ++i)
            #pragma unroll
            for (int r = 0; r < 4; ++r) { p0[i][r] = 0.f; p1[i][r] = 0.f; }
        #pragma unroll
        for (int j = 0; j < 4; ++j) {
            int cn = bn + wc * 64 + j * 16 + l15;
            float bv = bias[cn];
            float w30 = W3[cn * 2 + 0], w31 = W3[cn * 2 + 1];
            #pragma unroll
            for (int i = 0; i < 4; ++i)
                #pragma unroll
                for (int r = 0; r < 4; ++r) {
                    float v = fmaxf(acc[i][j][r] + bv, 0.f);
                    p0[i][r] += v * w30;
                    p1[i][r] += v * w31;
                }
        }
        #pragma unroll
        for (int i = 0; i < 4; ++i)
            #pragma unroll
            for (int r = 0; r < 4; ++r) {
                float q0 = p0[i][r], q1 = p1[i][r];
                #pragma unroll
                for (int off = 1; off < 16; off <<= 1) {
                    q0 += __shfl_xor(q0, off);
                    q1 += __shfl_xor(q1, off);
                }
                if (l15 == 0) {
                    int rm = bm + wr * 64 + i * 16 + kg * 4 + r;
                    if (rm < M) {
                        atomicAdd(&hw3[rm * 2 + 0], q0);
                        atomicAdd(&hw3[rm * 2 + 1], q1);
                    }
                }
            }
    }
}

// ---------------- layer-3 aggregation (2 channels) ---------------------------
__global__ void agg3(const float* __restrict__ hw3, const float* __restrict__ dinv,
                     const int* __restrict__ rowptr, const int* __restrict__ col,
                     const float* __restrict__ b3, float* __restrict__ out) {
    int n = blockIdx.x * blockDim.x + threadIdx.x;
    if (n >= NN) return;
    float a0 = 0.f, a1 = 0.f;
    int beg = rowptr[n], end = rowptr[n + 1];
    for (int j = beg; j < end; ++j) {
        int s = col[j];
        float w = dinv[s];
        float2 v = ((const float2*)hw3)[s];
        a0 += w * v.x;
        a1 += w * v.y;
    }
    float dn = dinv[n];
    float2 sv = ((const float2*)hw3)[n];
    out[n * 2 + 0] = dn * (a0 + dn * sv.x) + b3[0];
    out[n * 2 + 1] = dn * (a1 + dn * sv.y) + b3[1];
}

extern "C" void kernel_launch(void* const* d_in, const int* in_sizes, int n_in,
                              void* d_out, int out_size, void* d_ws, size_t ws_size,
                              hipStream_t stream) {
    const float* x   = (const float*)d_in[0];
    const int*   ebf = (const int*)d_in[1];
    const float* W1  = (const float*)d_in[2];
    const float* b1  = (const float*)d_in[3];
    const float* W2  = (const float*)d_in[4];
    const float* b2  = (const float*)d_in[5];
    const float* W3  = (const float*)d_in[6];
    const float* b3  = (const float*)d_in[7];
    float* out = (float*)d_out;

    char* ws = (char*)d_ws;
    size_t off = 0;
    auto carve = [&](size_t bytes) -> char* {
        char* p = ws + off;
        off += (bytes + 255) & ~(size_t)255;
        return p;
    };
    int*    flag   = (int*)   carve(256);
    int*    cnt    = (int*)   carve((size_t)NN * 4);
    float*  dinv   = (float*) carve((size_t)NN * 4);
    int*    rowptr = (int*)   carve((size_t)(NN + 1) * 4);
    int*    fillpos= (int*)   carve((size_t)NN * 4);
    int*    bsum   = (int*)   carve(256 * 4);
    int*    col    = (int*)   carve((size_t)NE * 4);
    ushort* xb     = (ushort*)carve((size_t)NN * XBP * 2);
    ushort* W1thi  = (ushort*)carve((size_t)HID * K1P * 2);
    ushort* W1tlo  = (ushort*)carve((size_t)HID * K1P * 2);
    ushort* W2thi  = (ushort*)carve((size_t)HID * HID * 2);
    ushort* W2tlo  = (ushort*)carve((size_t)HID * HID * 2);
    ushort* a1hi   = (ushort*)carve((size_t)NN * K1P * 2);
    ushort* a1lo   = (ushort*)carve((size_t)NN * K1P * 2);
    ushort* h1b    = (ushort*)carve((size_t)NN * HID * 2);
    ushort* a2hi   = (ushort*)carve((size_t)NN * HID * 2);
    ushort* a2lo   = (ushort*)carve((size_t)NN * HID * 2);
    float*  hw3    = (float*) carve((size_t)NN * OUTC * 4);
    (void)ws_size; (void)n_in; (void)in_sizes; (void)out_size;

    const int SCAN_G = (NN + 255) / 256;
    const int EG     = (NE + 255) / 256;

    hipMemsetAsync(cnt, 0, (size_t)NN * 4, stream);
    hipMemsetAsync(hw3, 0, (size_t)NN * OUTC * 4, stream);
    detect_fmt<<<1, 64, 0, stream>>>(ebf, flag);
    deg_hist<<<EG, 256, 0, stream>>>(ebf, flag, cnt);
    dinv_kernel<<<SCAN_G, 256, 0, stream>>>(cnt, dinv);
    scan1<<<SCAN_G, 256, 0, stream>>>(cnt, rowptr, bsum);
    scan2<<<1, 256, 0, stream>>>(bsum, SCAN_G);
    scan3<<<SCAN_G, 256, 0, stream>>>(rowptr, bsum, fillpos);
    fill_csr<<<EG, 256, 0, stream>>>(ebf, flag, fillpos, col);
    conv_x<<<((size_t)NN * XBP + 255) / 256, 256, 0, stream>>>(x, xb);
    decomp_w1<<<(HID * K1P) / 256, 256, 0, stream>>>(W1, W1thi, W1tlo);
    decomp_w2<<<(HID * HID) / 256, 256, 0, stream>>>(W2, W2thi, W2tlo);

    // layer 1: bf16 gather-aggregate x, MFMA 128->256 + relu -> bf16 h1
    agg1b<<<NN, 256, 0, stream>>>(xb, x, dinv, rowptr, col, a1hi, a1lo);
    {
        dim3 g((NN + 127) / 128, HID / 128);
        gemm_mfma<1><<<g, 256, 0, stream>>>(a1hi, a1lo, W1thi, W1tlo, b1, h1b,
                                            nullptr, nullptr, NN, K1P, HID);
    }
    // layer 2: bf16 gather-aggregate h1, MFMA 256->256 + relu, fused @W3 -> hw3
    agg2b<<<NN, 256, 0, stream>>>(h1b, dinv, rowptr, col, a2hi, a2lo);
    {
        dim3 g((NN + 127) / 128, HID / 128);
        gemm_mfma<2><<<g, 256, 0, stream>>>(a2hi, a2lo, W2thi, W2tlo, b2, nullptr,
                                            W3, hw3, NN, HID, HID);
    }
    // layer 3: 2-channel aggregation + bias
    agg3<<<SCAN_G, 256, 0, stream>>>(hw3, dinv, rowptr, col, b3, out);
}

// Round 5
// 529.356 us; speedup vs baseline: 1.5227x; 1.1116x over previous
//
#include <hip/hip_runtime.h>
#include <hip/hip_bf16.h>
#include <stdint.h>

#define NN 50000
#define NE 1600000
#define INC 116
#define XBP 128     // bf16-padded x row stride (16 x 16B chunks, 256B-aligned rows)
#define K1P 128     // padded K for layer-1 GEMM
#define HID 256
#define OUTC 2

typedef float f32x4 __attribute__((ext_vector_type(4)));
typedef short s16x8 __attribute__((ext_vector_type(8)));

// bf16 helpers (round-to-nearest-even), bit-level
__device__ __forceinline__ ushort f2bf(float v) {
    uint32_t u = __float_as_uint(v);
    return (ushort)((u + 0x7FFFu + ((u >> 16) & 1u)) >> 16);
}
__device__ __forceinline__ float bf2f(ushort b) {
    return __uint_as_float(((uint32_t)b) << 16);
}
__device__ __forceinline__ float bflo(uint32_t u) { return __uint_as_float(u << 16); }
__device__ __forceinline__ float bfhi(uint32_t u) { return __uint_as_float(u & 0xFFFF0000u); }

// ---------------- edge-index format hedge (int32 vs int64) ----------------
__global__ void detect_fmt(const int* __restrict__ ebuf, int* __restrict__ flag) {
    int v = ebuf[2 * threadIdx.x + 1];
    unsigned long long b = __ballot(v != 0);
    if (threadIdx.x == 0) flag[0] = (b == 0ULL) ? 1 : 0;
}

__device__ __forceinline__ int edge_at(const int* __restrict__ ebuf, int is64, int idx) {
    return is64 ? ebuf[2 * idx] : ebuf[idx];
}

// ---------------- degree histogram ----------------
__global__ void deg_hist(const int* __restrict__ ebuf, const int* __restrict__ flag,
                         int* __restrict__ cnt) {
    int e = blockIdx.x * blockDim.x + threadIdx.x;
    if (e >= NE) return;
    int is64 = flag[0];
    int d = edge_at(ebuf, is64, NE + e);
    atomicAdd(&cnt[d], 1);
}

__global__ void dinv_kernel(const int* __restrict__ cnt, float* __restrict__ dinv) {
    int n = blockIdx.x * blockDim.x + threadIdx.x;
    if (n < NN) dinv[n] = rsqrtf((float)cnt[n] + 1.0f);
}

// ---------------- prefix scan ----------------
__global__ void scan1(const int* __restrict__ cnt, int* __restrict__ rowptr,
                      int* __restrict__ bsum) {
    __shared__ int s[256];
    int tid = threadIdx.x;
    int i = blockIdx.x * 256 + tid;
    int v = (i < NN) ? cnt[i] : 0;
    s[tid] = v;
    __syncthreads();
    for (int off = 1; off < 256; off <<= 1) {
        int t = (tid >= off) ? s[tid - off] : 0;
        __syncthreads();
        s[tid] += t;
        __syncthreads();
    }
    if (i < NN) rowptr[i] = s[tid] - v;
    if (tid == 255) bsum[blockIdx.x] = s[255];
}

__global__ void scan2(int* __restrict__ bsum, int nblocks) {
    __shared__ int s[256];
    int tid = threadIdx.x;
    int v = (tid < nblocks) ? bsum[tid] : 0;
    s[tid] = v;
    __syncthreads();
    for (int off = 1; off < 256; off <<= 1) {
        int t = (tid >= off) ? s[tid - off] : 0;
        __syncthreads();
        s[tid] += t;
        __syncthreads();
    }
    if (tid < nblocks) bsum[tid] = s[tid] - v;
}

__global__ void scan3(int* __restrict__ rowptr, const int* __restrict__ bsum,
                      int* __restrict__ fillpos) {
    int i = blockIdx.x * 256 + threadIdx.x;
    if (i < NN) {
        int r = rowptr[i] + bsum[blockIdx.x];
        rowptr[i] = r;
        fillpos[i] = r;
        if (i == NN - 1) rowptr[NN] = NE;
    }
}

// ---------------- XCD-local CSR fill ----------------
// Block b (round-robin: XCD = b%8) handles dst range [(b&7)*6250, +6250).
// All col-writes for a node range come from one XCD -> lines merge in its L2.
// Perf heuristic only: wrong mapping = old perf, correctness unaffected.
__global__ void __launch_bounds__(256)
fill_csr2(const int* __restrict__ ebuf, const int* __restrict__ flag,
          int* __restrict__ fillpos, int* __restrict__ col) {
    int rng = blockIdx.x & 7;
    int lo = rng * (NN / 8), hi = lo + (NN / 8);   // 8*6250 = 50000 exact
    int is64 = flag[0];
    int stride = (gridDim.x >> 3) * 256;
    for (int e = (blockIdx.x >> 3) * 256 + threadIdx.x; e < NE; e += stride) {
        int d = edge_at(ebuf, is64, NE + e);
        if (d >= lo && d < hi) {
            int s = edge_at(ebuf, is64, e);
            int p = atomicAdd(&fillpos[d], 1);
            col[p] = s;
        }
    }
}

// ---------------- x -> bf16 padded [NN][128] ----------------
__global__ void conv_x(const float* __restrict__ x, ushort* __restrict__ xb) {
    int i = blockIdx.x * 256 + threadIdx.x;
    if (i >= NN * XBP) return;
    int n = i >> 7, c = i & 127;
    xb[i] = (c < INC) ? f2bf(x[(size_t)n * INC + c]) : (ushort)0;
}

// ---------------- weight decompose + transpose ----------------
__global__ void decomp_w1(const float* __restrict__ W, ushort* __restrict__ hi,
                          ushort* __restrict__ lo) {
    int i = blockIdx.x * 256 + threadIdx.x;   // 256*128
    int n = i >> 7, k = i & 127;
    float v = (k < INC) ? W[k * HID + n] : 0.f;
    ushort h = f2bf(v);
    hi[n * K1P + k] = h;
    lo[n * K1P + k] = f2bf(v - bf2f(h));
}

__global__ void decomp_w2(const float* __restrict__ W, ushort* __restrict__ hi,
                          ushort* __restrict__ lo) {
    int i = blockIdx.x * 256 + threadIdx.x;   // 256*256
    int n = i >> 8, k = i & 255;
    float v = W[k * HID + n];
    ushort h = f2bf(v);
    hi[n * HID + k] = h;
    lo[n * HID + k] = f2bf(v - bf2f(h));
}

// ---------------- layer-1 aggregate: gather bf16 x [NN][128] ----------------
// out[n] = dinv[n]*(sum_s dinv[s]*x[s] + dinv[n]*x[n]); self term from fp32 x.
// 16 groups x 16 lanes; lane c handles 16B chunk c (8 channels). Rows 256B-aligned.
__global__ void __launch_bounds__(256)
agg1b(const ushort* __restrict__ xb, const float* __restrict__ x,
      const float* __restrict__ dinv, const int* __restrict__ rowptr,
      const int* __restrict__ col, ushort* __restrict__ ohi, ushort* __restrict__ olo) {
    __shared__ float red[16][16][8];
    int n = blockIdx.x, tid = threadIdx.x;
    int g = tid >> 4, c = tid & 15;
    int beg = rowptr[n], end = rowptr[n + 1];
    {
        float a0=0.f,a1=0.f,a2=0.f,a3=0.f,a4=0.f,a5=0.f,a6=0.f,a7=0.f;
        const ushort* hc = xb + c * 8;
        int j = beg + g;
        for (; j + 16 < end; j += 32) {
            int s0 = col[j], s1 = col[j + 16];
            float w0 = dinv[s0], w1 = dinv[s1];
            uint4 u0 = *(const uint4*)(hc + (size_t)s0 * XBP);
            uint4 u1 = *(const uint4*)(hc + (size_t)s1 * XBP);
            a0 += w0 * bflo(u0.x) + w1 * bflo(u1.x);
            a1 += w0 * bfhi(u0.x) + w1 * bfhi(u1.x);
            a2 += w0 * bflo(u0.y) + w1 * bflo(u1.y);
            a3 += w0 * bfhi(u0.y) + w1 * bfhi(u1.y);
            a4 += w0 * bflo(u0.z) + w1 * bflo(u1.z);
            a5 += w0 * bfhi(u0.z) + w1 * bfhi(u1.z);
            a6 += w0 * bflo(u0.w) + w1 * bflo(u1.w);
            a7 += w0 * bfhi(u0.w) + w1 * bfhi(u1.w);
        }
        if (j < end) {
            int s0 = col[j];
            float w0 = dinv[s0];
            uint4 u0 = *(const uint4*)(hc + (size_t)s0 * XBP);
            a0 += w0 * bflo(u0.x); a1 += w0 * bfhi(u0.x);
            a2 += w0 * bflo(u0.y); a3 += w0 * bfhi(u0.y);
            a4 += w0 * bflo(u0.z); a5 += w0 * bfhi(u0.z);
            a6 += w0 * bflo(u0.w); a7 += w0 * bfhi(u0.w);
        }
        red[g][c][0]=a0; red[g][c][1]=a1; red[g][c][2]=a2; red[g][c][3]=a3;
        red[g][c][4]=a4; red[g][c][5]=a5; red[g][c][6]=a6; red[g][c][7]=a7;
    }
    __syncthreads();
    int t = tid;
    if (t < K1P) {
        float s = 0.f;
        #pragma unroll
        for (int gg = 0; gg < 16; ++gg) s += red[gg][t >> 3][t & 7];
        float self = (t < INC) ? x[(size_t)n * INC + t] : 0.f;
        float dn = dinv[n];
        float r = dn * (s + dn * self);
        ushort h = f2bf(r);
        ohi[(size_t)n * K1P + t] = h;
        olo[(size_t)n * K1P + t] = f2bf(r - bf2f(h));
    }
}

// ---------------- layer-2 aggregate: gather bf16 h1 [NN][256] ----------------
// 8 groups x 32 lanes; lane c handles 16B chunk c (8 channels).
__global__ void __launch_bounds__(256)
agg2b(const ushort* __restrict__ hb, const float* __restrict__ dinv,
      const int* __restrict__ rowptr, const int* __restrict__ col,
      ushort* __restrict__ ohi, ushort* __restrict__ olo) {
    __shared__ float red[8][32][8];
    int n = blockIdx.x, tid = threadIdx.x;
    int g = tid >> 5, c = tid & 31;
    int beg = rowptr[n], end = rowptr[n + 1];
    {
        float a0=0.f,a1=0.f,a2=0.f,a3=0.f,a4=0.f,a5=0.f,a6=0.f,a7=0.f;
        const ushort* hc = hb + c * 8;
        int j = beg + g;
        for (; j + 8 < end; j += 16) {
            int s0 = col[j], s1 = col[j + 8];
            float w0 = dinv[s0], w1 = dinv[s1];
            uint4 u0 = *(const uint4*)(hc + (size_t)s0 * HID);
            uint4 u1 = *(const uint4*)(hc + (size_t)s1 * HID);
            a0 += w0 * bflo(u0.x) + w1 * bflo(u1.x);
            a1 += w0 * bfhi(u0.x) + w1 * bfhi(u1.x);
            a2 += w0 * bflo(u0.y) + w1 * bflo(u1.y);
            a3 += w0 * bfhi(u0.y) + w1 * bfhi(u1.y);
            a4 += w0 * bflo(u0.z) + w1 * bflo(u1.z);
            a5 += w0 * bfhi(u0.z) + w1 * bfhi(u1.z);
            a6 += w0 * bflo(u0.w) + w1 * bflo(u1.w);
            a7 += w0 * bfhi(u0.w) + w1 * bfhi(u1.w);
        }
        if (j < end) {
            int s0 = col[j];
            float w0 = dinv[s0];
            uint4 u0 = *(const uint4*)(hc + (size_t)s0 * HID);
            a0 += w0 * bflo(u0.x); a1 += w0 * bfhi(u0.x);
            a2 += w0 * bflo(u0.y); a3 += w0 * bfhi(u0.y);
            a4 += w0 * bflo(u0.z); a5 += w0 * bfhi(u0.z);
            a6 += w0 * bflo(u0.w); a7 += w0 * bfhi(u0.w);
        }
        red[g][c][0]=a0; red[g][c][1]=a1; red[g][c][2]=a2; red[g][c][3]=a3;
        red[g][c][4]=a4; red[g][c][5]=a5; red[g][c][6]=a6; red[g][c][7]=a7;
    }
    __syncthreads();
    int t = tid;
    float s = 0.f;
    #pragma unroll
    for (int gg = 0; gg < 8; ++gg) s += red[gg][t >> 3][t & 7];
    float dn = dinv[n];
    float self = bf2f(hb[(size_t)n * HID + t]);
    float r = dn * (s + dn * self);
    ushort h = f2bf(r);
    ohi[(size_t)n * HID + t] = h;
    olo[(size_t)n * HID + t] = f2bf(r - bf2f(h));
}

// ---------------- MFMA GEMM, split-bf16 fp32 emulation -----------------------
// MODE 1: C = bf16( relu(A@Bt + bias) )           (layer 1 -> h1b)
// MODE 2: fused layer-3: v = relu(A@Bt + bias); atomicAdd hw3[row] += v @ W3
template <int MODE>
__global__ void __launch_bounds__(256)
gemm_mfma(const ushort* __restrict__ Ahi, const ushort* __restrict__ Alo,
          const ushort* __restrict__ Bhi, const ushort* __restrict__ Blo,
          const float* __restrict__ bias, ushort* __restrict__ Cb,
          const float* __restrict__ W3, float* __restrict__ hw3,
          int M, int K, int Nn) {
    constexpr int BM = 128, BN = 128, BK = 32, LDK = BK + 8;
    __shared__ ushort sAh[BM * LDK], sAl[BM * LDK];
    __shared__ ushort sBh[BN * LDK], sBl[BN * LDK];
    int tid = threadIdx.x;
    int w = tid >> 6, l = tid & 63;
    int wr = w >> 1, wc = w & 1;
    int bm = blockIdx.x * BM, bn = blockIdx.y * BN;
    int l15 = l & 15, kg = l >> 4;
    f32x4 zero = {0.f, 0.f, 0.f, 0.f};
    f32x4 acc[4][4];
    #pragma unroll
    for (int i = 0; i < 4; ++i)
        #pragma unroll
        for (int j = 0; j < 4; ++j) acc[i][j] = zero;

    for (int kb = 0; kb < K; kb += BK) {
        #pragma unroll
        for (int it = 0; it < 2; ++it) {
            int cc = tid + it * 256;
            int row = cc >> 2, kp = (cc & 3) * 8;
            int ar = bm + row;
            float4 z4 = make_float4(0.f, 0.f, 0.f, 0.f);
            float4 avh = z4, avl = z4;
            if (ar < M) {
                avh = *(const float4*)(Ahi + (size_t)ar * K + kb + kp);
                avl = *(const float4*)(Alo + (size_t)ar * K + kb + kp);
            }
            *(float4*)&sAh[row * LDK + kp] = avh;
            *(float4*)&sAl[row * LDK + kp] = avl;
            int br = bn + row;  // Nn == 256 always covers
            float4 bvh = *(const float4*)(Bhi + (size_t)br * K + kb + kp);
            float4 bvl = *(const float4*)(Blo + (size_t)br * K + kb + kp);
            *(float4*)&sBh[row * LDK + kp] = bvh;
            *(float4*)&sBl[row * LDK + kp] = bvl;
        }
        __syncthreads();
        s16x8 ah[4], al[4], bh[4], bl[4];
        #pragma unroll
        for (int i = 0; i < 4; ++i) {
            int arow = wr * 64 + i * 16 + l15;
            ah[i] = *(const s16x8*)&sAh[arow * LDK + kg * 8];
            al[i] = *(const s16x8*)&sAl[arow * LDK + kg * 8];
            int brow = wc * 64 + i * 16 + l15;
            bh[i] = *(const s16x8*)&sBh[brow * LDK + kg * 8];
            bl[i] = *(const s16x8*)&sBl[brow * LDK + kg * 8];
        }
        #pragma unroll
        for (int i = 0; i < 4; ++i)
            #pragma unroll
            for (int j = 0; j < 4; ++j) {
                acc[i][j] = __builtin_amdgcn_mfma_f32_16x16x32_bf16(ah[i], bh[j], acc[i][j], 0, 0, 0);
                acc[i][j] = __builtin_amdgcn_mfma_f32_16x16x32_bf16(ah[i], bl[j], acc[i][j], 0, 0, 0);
                acc[i][j] = __builtin_amdgcn_mfma_f32_16x16x32_bf16(al[i], bh[j], acc[i][j], 0, 0, 0);
            }
        __syncthreads();
    }
    // C/D layout: col = l&15, row = (l>>4)*4 + r
    if (MODE == 1) {
        #pragma unroll
        for (int j = 0; j < 4; ++j) {
            int cn = bn + wc * 64 + j * 16 + l15;
            float bv = bias[cn];
            #pragma unroll
            for (int i = 0; i < 4; ++i) {
                int rbase = bm + wr * 64 + i * 16 + kg * 4;
                #pragma unroll
                for (int r = 0; r < 4; ++r) {
                    int rm = rbase + r;
                    if (rm < M) {
                        float v = fmaxf(acc[i][j][r] + bv, 0.f);
                        Cb[(size_t)rm * Nn + cn] = f2bf(v);
                    }
                }
            }
        }
    } else {
        float p0[4][4], p1[4][4];
        #pragma unroll
        for (int i = 0; i < 4; ++i)
            #pragma unroll
            for (int r = 0; r < 4; ++r) { p0[i][r] = 0.f; p1[i][r] = 0.f; }
        #pragma unroll
        for (int j = 0; j < 4; ++j) {
            int cn = bn + wc * 64 + j * 16 + l15;
            float bv = bias[cn];
            float w30 = W3[cn * 2 + 0], w31 = W3[cn * 2 + 1];
            #pragma unroll
            for (int i = 0; i < 4; ++i)
                #pragma unroll
                for (int r = 0; r < 4; ++r) {
                    float v = fmaxf(acc[i][j][r] + bv, 0.f);
                    p0[i][r] += v * w30;
                    p1[i][r] += v * w31;
                }
        }
        #pragma unroll
        for (int i = 0; i < 4; ++i)
            #pragma unroll
            for (int r = 0; r < 4; ++r) {
                float q0 = p0[i][r], q1 = p1[i][r];
                #pragma unroll
                for (int off = 1; off < 16; off <<= 1) {
                    q0 += __shfl_xor(q0, off);
                    q1 += __shfl_xor(q1, off);
                }
                if (l15 == 0) {
                    int rm = bm + wr * 64 + i * 16 + kg * 4 + r;
                    if (rm < M) {
                        atomicAdd(&hw3[rm * 2 + 0], q0);
                        atomicAdd(&hw3[rm * 2 + 1], q1);
                    }
                }
            }
    }
}

// ---------------- layer-3 aggregation (2 channels) ---------------------------
__global__ void agg3(const float* __restrict__ hw3, const float* __restrict__ dinv,
                     const int* __restrict__ rowptr, const int* __restrict__ col,
                     const float* __restrict__ b3, float* __restrict__ out) {
    int n = blockIdx.x * blockDim.x + threadIdx.x;
    if (n >= NN) return;
    float a0 = 0.f, a1 = 0.f;
    int beg = rowptr[n], end = rowptr[n + 1];
    for (int j = beg; j < end; ++j) {
        int s = col[j];
        float w = dinv[s];
        float2 v = ((const float2*)hw3)[s];
        a0 += w * v.x;
        a1 += w * v.y;
    }
    float dn = dinv[n];
    float2 sv = ((const float2*)hw3)[n];
    out[n * 2 + 0] = dn * (a0 + dn * sv.x) + b3[0];
    out[n * 2 + 1] = dn * (a1 + dn * sv.y) + b3[1];
}

extern "C" void kernel_launch(void* const* d_in, const int* in_sizes, int n_in,
                              void* d_out, int out_size, void* d_ws, size_t ws_size,
                              hipStream_t stream) {
    const float* x   = (const float*)d_in[0];
    const int*   ebf = (const int*)d_in[1];
    const float* W1  = (const float*)d_in[2];
    const float* b1  = (const float*)d_in[3];
    const float* W2  = (const float*)d_in[4];
    const float* b2  = (const float*)d_in[5];
    const float* W3  = (const float*)d_in[6];
    const float* b3  = (const float*)d_in[7];
    float* out = (float*)d_out;

    char* ws = (char*)d_ws;
    size_t off = 0;
    auto carve = [&](size_t bytes) -> char* {
        char* p = ws + off;
        off += (bytes + 255) & ~(size_t)255;
        return p;
    };
    int*    flag   = (int*)   carve(256);
    int*    cnt    = (int*)   carve((size_t)NN * 4);
    float*  dinv   = (float*) carve((size_t)NN * 4);
    int*    rowptr = (int*)   carve((size_t)(NN + 1) * 4);
    int*    fillpos= (int*)   carve((size_t)NN * 4);
    int*    bsum   = (int*)   carve(256 * 4);
    int*    col    = (int*)   carve((size_t)NE * 4);
    ushort* xb     = (ushort*)carve((size_t)NN * XBP * 2);
    ushort* W1thi  = (ushort*)carve((size_t)HID * K1P * 2);
    ushort* W1tlo  = (ushort*)carve((size_t)HID * K1P * 2);
    ushort* W2thi  = (ushort*)carve((size_t)HID * HID * 2);
    ushort* W2tlo  = (ushort*)carve((size_t)HID * HID * 2);
    ushort* a1hi   = (ushort*)carve((size_t)NN * K1P * 2);
    ushort* a1lo   = (ushort*)carve((size_t)NN * K1P * 2);
    ushort* h1b    = (ushort*)carve((size_t)NN * HID * 2);
    ushort* a2hi   = (ushort*)carve((size_t)NN * HID * 2);
    ushort* a2lo   = (ushort*)carve((size_t)NN * HID * 2);
    float*  hw3    = (float*) carve((size_t)NN * OUTC * 4);
    (void)ws_size; (void)n_in; (void)in_sizes; (void)out_size;

    const int SCAN_G = (NN + 255) / 256;
    const int EG     = (NE + 255) / 256;

    hipMemsetAsync(cnt, 0, (size_t)NN * 4, stream);
    hipMemsetAsync(hw3, 0, (size_t)NN * OUTC * 4, stream);
    detect_fmt<<<1, 64, 0, stream>>>(ebf, flag);
    deg_hist<<<EG, 256, 0, stream>>>(ebf, flag, cnt);
    dinv_kernel<<<SCAN_G, 256, 0, stream>>>(cnt, dinv);
    scan1<<<SCAN_G, 256, 0, stream>>>(cnt, rowptr, bsum);
    scan2<<<1, 256, 0, stream>>>(bsum, SCAN_G);
    scan3<<<SCAN_G, 256, 0, stream>>>(rowptr, bsum, fillpos);
    fill_csr2<<<2048, 256, 0, stream>>>(ebf, flag, fillpos, col);
    conv_x<<<((size_t)NN * XBP + 255) / 256, 256, 0, stream>>>(x, xb);
    decomp_w1<<<(HID * K1P) / 256, 256, 0, stream>>>(W1, W1thi, W1tlo);
    decomp_w2<<<(HID * HID) / 256, 256, 0, stream>>>(W2, W2thi, W2tlo);

    // layer 1: bf16 gather-aggregate x, MFMA 128->256 + relu -> bf16 h1
    agg1b<<<NN, 256, 0, stream>>>(xb, x, dinv, rowptr, col, a1hi, a1lo);
    {
        dim3 g((NN + 127) / 128, HID / 128);
        gemm_mfma<1><<<g, 256, 0, stream>>>(a1hi, a1lo, W1thi, W1tlo, b1, h1b,
                                            nullptr, nullptr, NN, K1P, HID);
    }
    // layer 2: bf16 gather-aggregate h1, MFMA 256->256 + relu, fused @W3 -> hw3
    agg2b<<<NN, 256, 0, stream>>>(h1b, dinv, rowptr, col, a2hi, a2lo);
    {
        dim3 g((NN + 127) / 128, HID / 128);
        gemm_mfma<2><<<g, 256, 0, stream>>>(a2hi, a2lo, W2thi, W2tlo, b2, nullptr,
                                            W3, hw3, NN, HID, HID);
    }
    // layer 3: 2-channel aggregation + bias
    agg3<<<SCAN_G, 256, 0, stream>>>(hw3, dinv, rowptr, col, b3, out);
}